// Round 1
// baseline (786.123 us; speedup 1.0000x reference)
//
#include <hip/hip_runtime.h>
#include <math.h>

// ---------------------------------------------------------------------------
// ADCGNN amazon: N=50000 nodes, E=1.6M edges, IN=128, H=64, C=2, K=3
// Pipeline:
//   1. histogram(dst) -> count
//   2. single-block scan -> rowPtr, cursor, dinv
//   3. scatter -> srcSorted (CSR by dst)
//   4. dense l1: h1 = relu(X@W1+b1)
//   5. dense l2: h = relu(h1@W2+b2), hs = h*dinv
//   6. dense res: res = h@Wres+bres
//   7. spmm1: u1 = dinv*(A^T hs), u1s = u1*dinv
//   8. spmm2: u2 = dinv*(A^T u1s)
//   9. attn: branches -> softmax -> fin = [attn_fused | mean_fused]
//  10. fuse: fw MLP -> fused -> relu(@W3+b3) -> @W4+b4 -> logits
// ---------------------------------------------------------------------------

__device__ __forceinline__ void fma4(float4& acc, float s, const float4 w) {
    acc.x += s * w.x; acc.y += s * w.y; acc.z += s * w.z; acc.w += s * w.w;
}

// ----------------------------- graph build ---------------------------------

__global__ __launch_bounds__(256) void hist_k(const int* __restrict__ dst,
                                              int* __restrict__ count, int E) {
    int e = blockIdx.x * 256 + threadIdx.x;
    if (e < E) atomicAdd(&count[dst[e]], 1);
}

__global__ __launch_bounds__(1024) void scan_k(const int* __restrict__ count,
                                               int* __restrict__ rowPtr,
                                               int* __restrict__ cursor,
                                               float* __restrict__ dinv, int N) {
    __shared__ int wsum[16];
    __shared__ int carry;
    const int tid = threadIdx.x;
    const int lane = tid & 63;
    const int wid = tid >> 6;
    if (tid == 0) carry = 0;
    const int CH = 1024 * 8;
    for (int base = 0; base < N; base += CH) {
        __syncthreads();                  // prev iter fully done, carry visible
        int carry_local = carry;
        int i0 = base + tid * 8;
        int v[8];
        int s = 0;
        #pragma unroll
        for (int t = 0; t < 8; t++) {
            int i = i0 + t;
            v[t] = (i < N) ? count[i] : 0;
            s += v[t];
        }
        int x = s;                        // wave inclusive scan
        #pragma unroll
        for (int off = 1; off < 64; off <<= 1) {
            int y = __shfl_up(x, off, 64);
            if (lane >= off) x += y;
        }
        if (lane == 63) wsum[wid] = x;
        __syncthreads();
        if (wid == 0) {
            int wv = (lane < 16) ? wsum[lane] : 0;
            #pragma unroll
            for (int off = 1; off < 16; off <<= 1) {
                int y = __shfl_up(wv, off, 64);
                if (lane >= off) wv += y;
            }
            if (lane < 16) wsum[lane] = wv;
        }
        __syncthreads();
        int waveoff = carry_local + (wid ? wsum[wid - 1] : 0);
        int run = waveoff + (x - s);      // exclusive offset for this thread
        #pragma unroll
        for (int t = 0; t < 8; t++) {
            int i = i0 + t;
            if (i < N) {
                rowPtr[i] = run;
                cursor[i] = run;
                int d = v[t] > 1 ? v[t] : 1;
                dinv[i] = rsqrtf((float)d);
            }
            run += v[t];
        }
        if (tid == 0) carry = carry_local + wsum[15];
    }
    __syncthreads();
    if (tid == 0) rowPtr[N] = carry;
}

__global__ __launch_bounds__(256) void scatter_k(const int* __restrict__ src,
                                                 const int* __restrict__ dst,
                                                 int* __restrict__ cursor,
                                                 int* __restrict__ srcSorted, int E) {
    int e = blockIdx.x * 256 + threadIdx.x;
    if (e < E) {
        int p = atomicAdd(&cursor[dst[e]], 1);
        srcSorted[p] = src[e];
    }
}

// ----------------------------- dense layers --------------------------------
// One node per thread. acc[16] float4 = 64 outputs. Weight loads are
// wave-uniform -> expect scalar-load promotion. Input row prefetched 1 deep.

template <int K, bool RELU, bool SCALE>
__global__ __launch_bounds__(256) void dense_k(const float* __restrict__ Xg,
                                               const float* __restrict__ Wg,
                                               const float* __restrict__ bg,
                                               const float* __restrict__ dinv,
                                               float* __restrict__ outg,
                                               float* __restrict__ outsg, int N) {
    int n = blockIdx.x * 256 + threadIdx.x;
    if (n >= N) return;
    const float4* X = (const float4*)Xg + (size_t)n * (K / 4);
    const float4* W = (const float4*)Wg;
    const float4* B = (const float4*)bg;
    float4 acc[16];
    #pragma unroll
    for (int j = 0; j < 16; j++) acc[j] = B[j];
    float4 a = X[0];
    #pragma unroll 1
    for (int kc = 0; kc < K / 4; kc++) {
        float4 an = a;
        if (kc + 1 < K / 4) an = X[kc + 1];
        const float4* wrow = W + kc * 64;
        #pragma unroll
        for (int j = 0; j < 16; j++) {
            fma4(acc[j], a.x, wrow[j]);
            fma4(acc[j], a.y, wrow[16 + j]);
            fma4(acc[j], a.z, wrow[32 + j]);
            fma4(acc[j], a.w, wrow[48 + j]);
        }
        a = an;
    }
    float4* O = (float4*)outg + (size_t)n * 16;
    float di = SCALE ? dinv[n] : 0.f;
    float4* OS = SCALE ? ((float4*)outsg + (size_t)n * 16) : nullptr;
    #pragma unroll
    for (int j = 0; j < 16; j++) {
        float4 v = acc[j];
        if (RELU) {
            v.x = fmaxf(v.x, 0.f); v.y = fmaxf(v.y, 0.f);
            v.z = fmaxf(v.z, 0.f); v.w = fmaxf(v.w, 0.f);
        }
        O[j] = v;
        if (SCALE) {
            float4 vs = make_float4(v.x * di, v.y * di, v.z * di, v.w * di);
            OS[j] = vs;
        }
    }
}

// ----------------------------- SPMM gather ---------------------------------
// One 64-lane wave per node: lane = sub(0..3)*16 + q(0..15).
// Each iteration: 4 edges in flight, 16 lanes x float4 = full 64-float row.

__global__ __launch_bounds__(256) void spmm_k(const float4* __restrict__ xs,
                                              const int* __restrict__ srcs,
                                              const int* __restrict__ rowPtr,
                                              const float* __restrict__ dinv,
                                              float4* __restrict__ u,
                                              float4* __restrict__ us, int N) {
    int node = (blockIdx.x * 256 + threadIdx.x) >> 6;
    if (node >= N) return;                    // uniform per wave
    int lane = threadIdx.x & 63;
    int sub = lane >> 4;
    int q = lane & 15;
    int s0 = rowPtr[node], s1 = rowPtr[node + 1];
    float ax = 0.f, ay = 0.f, az = 0.f, aw = 0.f;
    for (int i = s0 + sub; i < s1; i += 4) {
        int s = srcs[i];
        float4 v = xs[(size_t)s * 16 + q];
        ax += v.x; ay += v.y; az += v.z; aw += v.w;
    }
    #pragma unroll
    for (int m = 16; m < 64; m <<= 1) {
        ax += __shfl_xor(ax, m, 64);
        ay += __shfl_xor(ay, m, 64);
        az += __shfl_xor(az, m, 64);
        aw += __shfl_xor(aw, m, 64);
    }
    if (sub == 0) {
        float di = dinv[node];
        float4 r = make_float4(ax * di, ay * di, az * di, aw * di);
        u[(size_t)node * 16 + q] = r;
        if (us) {
            float4 r2 = make_float4(r.x * di, r.y * di, r.z * di, r.w * di);
            us[(size_t)node * 16 + q] = r2;
        }
    }
}

// ----------------------------- attention -----------------------------------

struct F3 { float b0, b1, b2; };
__device__ __forceinline__ F3 mkbranch(float hv, float av, float bv) {
    F3 r;
    r.b0 = 0.75f * hv + 1.5f * av + 0.75f * bv;
    r.b1 = 1.5f * hv - 1.5f * bv;
    r.b2 = 0.75f * hv - 1.5f * av + 0.75f * bv;
    return r;
}

__global__ __launch_bounds__(256) void attn_k(const float4* __restrict__ h,
                                              const float4* __restrict__ u1,
                                              const float4* __restrict__ u2,
                                              const float* __restrict__ Wattn,
                                              const float* __restrict__ battn,
                                              float4* __restrict__ fin, int N) {
    int n = blockIdx.x * 256 + threadIdx.x;
    if (n >= N) return;
    const float4* H = h + (size_t)n * 16;
    const float4* A = u1 + (size_t)n * 16;
    const float4* Bv = u2 + (size_t)n * 16;
    const float4* Wa = (const float4*)Wattn;
    float s0 = 0.f, s1 = 0.f, s2 = 0.f;
    #pragma unroll
    for (int j = 0; j < 16; j++) {
        float4 hv = H[j], av = A[j], bv = Bv[j], w = Wa[j];
        #define BR_SC(c) { F3 r = mkbranch(hv.c, av.c, bv.c); \
            s0 += r.b0 * w.c; s1 += r.b1 * w.c; s2 += r.b2 * w.c; }
        BR_SC(x) BR_SC(y) BR_SC(z) BR_SC(w)
        #undef BR_SC
    }
    float ba = battn[0];
    s0 += ba; s1 += ba; s2 += ba;
    float m = fmaxf(s0, fmaxf(s1, s2));
    float e0 = expf(s0 - m), e1 = expf(s1 - m), e2 = expf(s2 - m);
    float inv = 1.f / (e0 + e1 + e2);
    float w0 = e0 * inv, w1 = e1 * inv, w2 = e2 * inv;
    float4* F = fin + (size_t)n * 32;
    #pragma unroll
    for (int j = 0; j < 16; j++) {
        float4 hv = H[j], av = A[j], bv = Bv[j];
        float4 af, mf;
        #define BR_AF(c) { F3 r = mkbranch(hv.c, av.c, bv.c); \
            af.c = w0 * r.b0 + w1 * r.b1 + w2 * r.b2; \
            mf.c = (r.b0 + r.b1 + r.b2) * (1.0f / 3.0f); }
        BR_AF(x) BR_AF(y) BR_AF(z) BR_AF(w)
        #undef BR_AF
        F[j] = af;
        F[16 + j] = mf;
    }
}

// ----------------------------- fusion tail ---------------------------------

__global__ __launch_bounds__(256) void fuse_k(const float4* __restrict__ fin,
                                              const float4* __restrict__ res,
                                              const float* __restrict__ Wf1,
                                              const float* __restrict__ bf1,
                                              const float* __restrict__ Wf2,
                                              const float* __restrict__ bf2,
                                              const float* __restrict__ W3,
                                              const float* __restrict__ b3,
                                              const float* __restrict__ W4,
                                              const float* __restrict__ b4,
                                              float2* __restrict__ out, int N) {
    int n = blockIdx.x * 256 + threadIdx.x;
    if (n >= N) return;
    const float4* F = fin + (size_t)n * 32;
    // t = relu(fin @ Wf1 + bf1), K=128
    const float4* Wf14 = (const float4*)Wf1;
    const float4* Bf1 = (const float4*)bf1;
    float4 t[16];
    #pragma unroll
    for (int j = 0; j < 16; j++) t[j] = Bf1[j];
    float4 a = F[0];
    #pragma unroll 1
    for (int kc = 0; kc < 32; kc++) {
        float4 an = a;
        if (kc + 1 < 32) an = F[kc + 1];
        const float4* wrow = Wf14 + kc * 64;
        #pragma unroll
        for (int j = 0; j < 16; j++) {
            fma4(t[j], a.x, wrow[j]);
            fma4(t[j], a.y, wrow[16 + j]);
            fma4(t[j], a.z, wrow[32 + j]);
            fma4(t[j], a.w, wrow[48 + j]);
        }
        a = an;
    }
    const float4* Wf24 = (const float4*)Wf2;
    float fwacc = bf2[0];
    #pragma unroll
    for (int j = 0; j < 16; j++) {
        float4 v = t[j];
        v.x = fmaxf(v.x, 0.f); v.y = fmaxf(v.y, 0.f);
        v.z = fmaxf(v.z, 0.f); v.w = fmaxf(v.w, 0.f);
        float4 w = Wf24[j];
        fwacc += v.x * w.x + v.y * w.y + v.z * w.z + v.w * w.w;
    }
    float fw = 1.f / (1.f + expf(-fwacc));
    float c_af = 0.1f * fw, c_mf = 1.f - fw;
    // g = relu(fused @ W3 + b3), fused = c_af*af + c_mf*mf + 0.8*res
    const float4* W34 = (const float4*)W3;
    const float4* B3 = (const float4*)b3;
    const float4* R = res + (size_t)n * 16;
    float4 g[16];
    #pragma unroll
    for (int j = 0; j < 16; j++) g[j] = B3[j];
    #pragma unroll 1
    for (int kc = 0; kc < 16; kc++) {
        float4 af = F[kc], mf = F[16 + kc], rv = R[kc];
        float4 f;
        f.x = c_af * af.x + c_mf * mf.x + 0.8f * rv.x;
        f.y = c_af * af.y + c_mf * mf.y + 0.8f * rv.y;
        f.z = c_af * af.z + c_mf * mf.z + 0.8f * rv.z;
        f.w = c_af * af.w + c_mf * mf.w + 0.8f * rv.w;
        const float4* wrow = W34 + kc * 64;
        #pragma unroll
        for (int j = 0; j < 16; j++) {
            fma4(g[j], f.x, wrow[j]);
            fma4(g[j], f.y, wrow[16 + j]);
            fma4(g[j], f.z, wrow[32 + j]);
            fma4(g[j], f.w, wrow[48 + j]);
        }
    }
    // logits = relu(g) @ W4 + b4
    const float2* W42 = (const float2*)W4;
    float l0 = b4[0], l1 = b4[1];
    #pragma unroll
    for (int j = 0; j < 16; j++) {
        float4 v = g[j];
        v.x = fmaxf(v.x, 0.f); v.y = fmaxf(v.y, 0.f);
        v.z = fmaxf(v.z, 0.f); v.w = fmaxf(v.w, 0.f);
        float2 wa = W42[j * 4 + 0], wb = W42[j * 4 + 1];
        float2 wc = W42[j * 4 + 2], wd = W42[j * 4 + 3];
        l0 += v.x * wa.x + v.y * wb.x + v.z * wc.x + v.w * wd.x;
        l1 += v.x * wa.y + v.y * wb.y + v.z * wc.y + v.w * wd.y;
    }
    out[n] = make_float2(l0, l1);
}

// ----------------------------- launch --------------------------------------

extern "C" void kernel_launch(void* const* d_in, const int* in_sizes, int n_in,
                              void* d_out, int out_size, void* d_ws, size_t ws_size,
                              hipStream_t stream) {
    const float* in_feat = (const float*)d_in[0];
    const int*   src     = (const int*)d_in[1];
    const int*   dst     = (const int*)d_in[2];
    const float* W1   = (const float*)d_in[3];
    const float* b1   = (const float*)d_in[4];
    const float* W2   = (const float*)d_in[5];
    const float* b2   = (const float*)d_in[6];
    const float* Wres = (const float*)d_in[7];
    const float* bres = (const float*)d_in[8];
    const float* Wattn = (const float*)d_in[9];
    const float* battn = (const float*)d_in[10];
    const float* Wf1  = (const float*)d_in[11];
    const float* bf1  = (const float*)d_in[12];
    const float* Wf2  = (const float*)d_in[13];
    const float* bf2  = (const float*)d_in[14];
    const float* W3   = (const float*)d_in[15];
    const float* b3   = (const float*)d_in[16];
    const float* W4   = (const float*)d_in[17];
    const float* b4   = (const float*)d_in[18];

    const int N = in_sizes[0] / 128;
    const int E = in_sizes[1];

    char* p = (char*)d_ws;
    auto take = [&](size_t bytes) -> char* {
        char* r = p;
        p += (bytes + 255) & ~(size_t)255;
        return r;
    };
    int*   count     = (int*)take((size_t)N * 4);
    int*   rowPtr    = (int*)take((size_t)(N + 1) * 4);
    int*   cursor    = (int*)take((size_t)N * 4);
    float* dinv      = (float*)take((size_t)N * 4);
    int*   srcSorted = (int*)take((size_t)E * 4);
    float* h1  = (float*)take((size_t)N * 256);
    float* h   = (float*)take((size_t)N * 256);
    float* hs  = (float*)take((size_t)N * 256);   // low half of fin after spmm1
    float* u1s = (float*)take((size_t)N * 256);   // high half of fin (contiguous with hs)
    float* res = (float*)take((size_t)N * 256);
    float* u1  = (float*)take((size_t)N * 256);
    float* u2  = h1;    // h1 dead after l2
    float* fin = hs;    // hs+u1s dead after spmm2; 2*N*64 contiguous floats

    hipMemsetAsync(count, 0, (size_t)N * 4, stream);
    int eb = (E + 255) / 256;
    int nb = (N + 255) / 256;
    int sb = ((N * 64) + 255) / 256;

    hist_k<<<eb, 256, 0, stream>>>(dst, count, E);
    scan_k<<<1, 1024, 0, stream>>>(count, rowPtr, cursor, dinv, N);
    scatter_k<<<eb, 256, 0, stream>>>(src, dst, cursor, srcSorted, E);

    dense_k<128, true, false><<<nb, 256, 0, stream>>>(in_feat, W1, b1, nullptr, h1, nullptr, N);
    dense_k<64, true, true><<<nb, 256, 0, stream>>>(h1, W2, b2, dinv, h, hs, N);
    dense_k<64, false, false><<<nb, 256, 0, stream>>>(h, Wres, bres, nullptr, res, nullptr, N);

    spmm_k<<<sb, 256, 0, stream>>>((const float4*)hs, srcSorted, rowPtr, dinv,
                                   (float4*)u1, (float4*)u1s, N);
    spmm_k<<<sb, 256, 0, stream>>>((const float4*)u1s, srcSorted, rowPtr, dinv,
                                   (float4*)u2, nullptr, N);

    attn_k<<<nb, 256, 0, stream>>>((const float4*)h, (const float4*)u1,
                                   (const float4*)u2, Wattn, battn, (float4*)fin, N);
    fuse_k<<<nb, 256, 0, stream>>>((const float4*)fin, (const float4*)res,
                                   Wf1, bf1, Wf2, bf2, W3, b3, W4, b4,
                                   (float2*)d_out, N);
}

// Round 2
// 462.168 us; speedup vs baseline: 1.7009x; 1.7009x over previous
//
#include <hip/hip_runtime.h>
#include <math.h>

// ---------------------------------------------------------------------------
// ADCGNN amazon: N=50000, E=1.6M, IN=128, H=64, C=2, K=3
//
// Graph build (no per-edge global atomics):
//   1. bucket_count: LDS hist over B=ceil(N/128) dst-buckets
//   2. bucket_scan: 1-wave scan -> bucketPtr/bucketCursor
//   3. bucket_scatter: per-block LDS multisplit, packed (localdst<<16|src)
//   4. csr_build: 1 block/bucket, LDS hist+scan+scatter -> srcSorted/rowPtr/dinv
// Dense/graph compute:
//   5. dense1: h1 = relu(X@W1+b1)
//   6. dense2res: h = relu(h1@W2+b2); hs = h*dinv; res = h@Wres+bres
//   7. spmm x2: u1 = dinv*(A^T hs), u1s = u1*dinv; u2 = dinv*(A^T u1s)
//   8. attnfuse: branches are linear in (h,u1,u2); mean_fused == h exactly;
//      attn_fused = ca*h+cb*u1+cc*u2 -> fw MLP -> W3 -> W4 -> logits
// ---------------------------------------------------------------------------

#define BSHIFT 7
#define BNODES 128
#define BMAX   512      // supports N <= 65536
#define EPT    32       // edges per thread in bucket kernels
#define CHUNK  (256 * EPT)
#define CAP    8192     // LDS staging capacity (edges) in csr_build

__device__ __forceinline__ void fma4(float4& acc, float s, const float4 w) {
    acc.x += s * w.x; acc.y += s * w.y; acc.z += s * w.z; acc.w += s * w.w;
}

// ----------------------------- graph build ---------------------------------

__global__ __launch_bounds__(256) void bucket_count_k(const int* __restrict__ dst,
                                                      int* __restrict__ bucketCount,
                                                      int E, int B) {
    __shared__ int cnt[BMAX];
    for (int i = threadIdx.x; i < B; i += 256) cnt[i] = 0;
    __syncthreads();
    int base = blockIdx.x * CHUNK;
    #pragma unroll
    for (int t = 0; t < EPT; t++) {
        int e = base + t * 256 + threadIdx.x;
        if (e < E) atomicAdd(&cnt[dst[e] >> BSHIFT], 1);
    }
    __syncthreads();
    for (int i = threadIdx.x; i < B; i += 256)
        if (cnt[i] > 0) atomicAdd(&bucketCount[i], cnt[i]);
}

__global__ __launch_bounds__(64) void bucket_scan_k(const int* __restrict__ bucketCount,
                                                    int* __restrict__ bucketPtr,
                                                    int* __restrict__ bucketCursor,
                                                    int* __restrict__ rowPtr,
                                                    int B, int N, int E) {
    int lane = threadIdx.x;
    const int PT = (BMAX + 63) / 64;   // 8
    int v[PT]; int s = 0;
    #pragma unroll
    for (int t = 0; t < PT; t++) {
        int i = lane * PT + t;
        v[t] = (i < B) ? bucketCount[i] : 0;
        s += v[t];
    }
    int x = s;
    #pragma unroll
    for (int off = 1; off < 64; off <<= 1) {
        int y = __shfl_up(x, off, 64);
        if (lane >= off) x += y;
    }
    int run = x - s;
    #pragma unroll
    for (int t = 0; t < PT; t++) {
        int i = lane * PT + t;
        if (i < B) { bucketPtr[i] = run; bucketCursor[i] = run; }
        run += v[t];
    }
    if (lane == 63) bucketPtr[B] = x;
    if (lane == 0) rowPtr[N] = E;
}

__global__ __launch_bounds__(256) void bucket_scatter_k(const int* __restrict__ src,
                                                        const int* __restrict__ dst,
                                                        int* __restrict__ bucketCursor,
                                                        int* __restrict__ ebuf,
                                                        int E, int B) {
    __shared__ int cnt[BMAX];
    __shared__ int base[BMAX];
    __shared__ int cur[BMAX];
    for (int i = threadIdx.x; i < B; i += 256) { cnt[i] = 0; cur[i] = 0; }
    __syncthreads();
    int cbase = blockIdx.x * CHUNK;
    int d[EPT];
    #pragma unroll
    for (int t = 0; t < EPT; t++) {
        int e = cbase + t * 256 + threadIdx.x;
        d[t] = (e < E) ? dst[e] : -1;
        if (d[t] >= 0) atomicAdd(&cnt[d[t] >> BSHIFT], 1);
    }
    __syncthreads();
    for (int i = threadIdx.x; i < B; i += 256)
        if (cnt[i] > 0) base[i] = atomicAdd(&bucketCursor[i], cnt[i]);
    __syncthreads();
    #pragma unroll
    for (int t = 0; t < EPT; t++) {
        int e = cbase + t * 256 + threadIdx.x;
        if (d[t] >= 0) {
            int b = d[t] >> BSHIFT;
            int c = atomicAdd(&cur[b], 1);
            int pack = (src[e] & 0xFFFF) | ((d[t] & (BNODES - 1)) << 16);
            ebuf[base[b] + c] = pack;
        }
    }
}

__global__ __launch_bounds__(256) void csr_build_k(const int* __restrict__ ebuf,
                                                   const int* __restrict__ bucketPtr,
                                                   int* __restrict__ rowPtr,
                                                   float* __restrict__ dinv,
                                                   int* __restrict__ srcSorted,
                                                   int N) {
    __shared__ int deg[BNODES];
    __shared__ int rp[BNODES + 1];
    __shared__ int cur[BNODES];
    __shared__ int stage[CAP];
    int b = blockIdx.x;
    int nodeBase = b << BSHIFT;
    int nNodes = min(BNODES, N - nodeBase);
    int eBase = bucketPtr[b];
    int eCnt = bucketPtr[b + 1] - eBase;
    for (int i = threadIdx.x; i < BNODES; i += 256) deg[i] = 0;
    __syncthreads();
    for (int i = threadIdx.x; i < eCnt; i += 256)
        atomicAdd(&deg[(ebuf[eBase + i] >> 16) & (BNODES - 1)], 1);
    __syncthreads();
    if (threadIdx.x < 64) {
        int lane = threadIdx.x;
        int d0 = deg[2 * lane], d1 = deg[2 * lane + 1];
        int s = d0 + d1;
        int x = s;
        #pragma unroll
        for (int off = 1; off < 64; off <<= 1) {
            int y = __shfl_up(x, off, 64);
            if (lane >= off) x += y;
        }
        int ex = x - s;
        rp[2 * lane] = ex;
        rp[2 * lane + 1] = ex + d0;
        cur[2 * lane] = ex;
        cur[2 * lane + 1] = ex + d0;
        if (lane == 63) rp[BNODES] = x;
    }
    __syncthreads();
    for (int j = threadIdx.x; j < nNodes; j += 256) {
        rowPtr[nodeBase + j] = eBase + rp[j];
        int dg = deg[j];
        dinv[nodeBase + j] = rsqrtf((float)(dg > 1 ? dg : 1));
    }
    if (eCnt <= CAP) {
        for (int i = threadIdx.x; i < eCnt; i += 256) {
            int p = ebuf[eBase + i];
            int ld = (p >> 16) & (BNODES - 1);
            int pos = atomicAdd(&cur[ld], 1);
            stage[pos] = p & 0xFFFF;
        }
        __syncthreads();
        for (int i = threadIdx.x; i < eCnt; i += 256)
            srcSorted[eBase + i] = stage[i];
    } else {   // overflow fallback (never hit for this input, kept for safety)
        for (int i = threadIdx.x; i < eCnt; i += 256) {
            int p = ebuf[eBase + i];
            int ld = (p >> 16) & (BNODES - 1);
            int pos = atomicAdd(&cur[ld], 1);
            srcSorted[eBase + pos] = p & 0xFFFF;
        }
    }
}

// ----------------------------- dense layers --------------------------------

__global__ __launch_bounds__(256) void dense1_k(const float* __restrict__ Xg,
                                                const float* __restrict__ Wg,
                                                const float* __restrict__ bg,
                                                float* __restrict__ outg, int N) {
    int n = blockIdx.x * 256 + threadIdx.x;
    if (n >= N) return;
    const float4* X = (const float4*)Xg + (size_t)n * 32;
    const float4* W = (const float4*)Wg;
    const float4* B = (const float4*)bg;
    float4 acc[16];
    #pragma unroll
    for (int j = 0; j < 16; j++) acc[j] = B[j];
    float4 a = X[0];
    #pragma unroll 1
    for (int kc = 0; kc < 32; kc++) {
        float4 an = a;
        if (kc + 1 < 32) an = X[kc + 1];
        const float4* wrow = W + kc * 64;
        #pragma unroll
        for (int j = 0; j < 16; j++) {
            fma4(acc[j], a.x, wrow[j]);
            fma4(acc[j], a.y, wrow[16 + j]);
            fma4(acc[j], a.z, wrow[32 + j]);
            fma4(acc[j], a.w, wrow[48 + j]);
        }
        a = an;
    }
    float4* O = (float4*)outg + (size_t)n * 16;
    #pragma unroll
    for (int j = 0; j < 16; j++) {
        float4 v = acc[j];
        v.x = fmaxf(v.x, 0.f); v.y = fmaxf(v.y, 0.f);
        v.z = fmaxf(v.z, 0.f); v.w = fmaxf(v.w, 0.f);
        O[j] = v;
    }
}

__global__ __launch_bounds__(256) void dense2res_k(const float* __restrict__ h1g,
                                                   const float* __restrict__ W2,
                                                   const float* __restrict__ b2,
                                                   const float* __restrict__ Wres,
                                                   const float* __restrict__ bres,
                                                   const float* __restrict__ dinv,
                                                   float* __restrict__ hg,
                                                   float* __restrict__ hsg,
                                                   float* __restrict__ resg, int N) {
    int n = blockIdx.x * 256 + threadIdx.x;
    if (n >= N) return;
    const float4* X = (const float4*)h1g + (size_t)n * 16;
    const float4* W = (const float4*)W2;
    const float4* B = (const float4*)b2;
    float4 acc[16];
    #pragma unroll
    for (int j = 0; j < 16; j++) acc[j] = B[j];
    float4 a = X[0];
    #pragma unroll 1
    for (int kc = 0; kc < 16; kc++) {
        float4 an = a;
        if (kc + 1 < 16) an = X[kc + 1];
        const float4* wrow = W + kc * 64;
        #pragma unroll
        for (int j = 0; j < 16; j++) {
            fma4(acc[j], a.x, wrow[j]);
            fma4(acc[j], a.y, wrow[16 + j]);
            fma4(acc[j], a.z, wrow[32 + j]);
            fma4(acc[j], a.w, wrow[48 + j]);
        }
        a = an;
    }
    float di = dinv[n];
    float4* H = (float4*)hg + (size_t)n * 16;
    float4* HS = (float4*)hsg + (size_t)n * 16;
    #pragma unroll
    for (int j = 0; j < 16; j++) {
        float4 v = acc[j];
        v.x = fmaxf(v.x, 0.f); v.y = fmaxf(v.y, 0.f);
        v.z = fmaxf(v.z, 0.f); v.w = fmaxf(v.w, 0.f);
        acc[j] = v;
        H[j] = v;
        HS[j] = make_float4(v.x * di, v.y * di, v.z * di, v.w * di);
    }
    // res = h @ Wres + bres, h in registers
    const float4* WR = (const float4*)Wres;
    const float4* BR = (const float4*)bres;
    float4 acc2[16];
    #pragma unroll
    for (int j = 0; j < 16; j++) acc2[j] = BR[j];
    #pragma unroll 1
    for (int kc = 0; kc < 16; kc++) {
        float4 a2 = acc[kc];
        const float4* wrow = WR + kc * 64;
        #pragma unroll
        for (int j = 0; j < 16; j++) {
            fma4(acc2[j], a2.x, wrow[j]);
            fma4(acc2[j], a2.y, wrow[16 + j]);
            fma4(acc2[j], a2.z, wrow[32 + j]);
            fma4(acc2[j], a2.w, wrow[48 + j]);
        }
    }
    float4* R = (float4*)resg + (size_t)n * 16;
    #pragma unroll
    for (int j = 0; j < 16; j++) R[j] = acc2[j];
}

// ----------------------------- SPMM gather ---------------------------------

__global__ __launch_bounds__(256) void spmm_k(const float4* __restrict__ xs,
                                              const int* __restrict__ srcs,
                                              const int* __restrict__ rowPtr,
                                              const float* __restrict__ dinv,
                                              float4* __restrict__ u,
                                              float4* __restrict__ us, int N) {
    int node = (blockIdx.x * 256 + threadIdx.x) >> 6;
    if (node >= N) return;
    int lane = threadIdx.x & 63;
    int sub = lane >> 4;
    int q = lane & 15;
    int s0 = rowPtr[node], s1 = rowPtr[node + 1];
    float ax = 0.f, ay = 0.f, az = 0.f, aw = 0.f;
    for (int i = s0 + sub; i < s1; i += 4) {
        int s = srcs[i];
        float4 v = xs[(size_t)s * 16 + q];
        ax += v.x; ay += v.y; az += v.z; aw += v.w;
    }
    #pragma unroll
    for (int m = 16; m < 64; m <<= 1) {
        ax += __shfl_xor(ax, m, 64);
        ay += __shfl_xor(ay, m, 64);
        az += __shfl_xor(az, m, 64);
        aw += __shfl_xor(aw, m, 64);
    }
    if (sub == 0) {
        float di = dinv[node];
        float4 r = make_float4(ax * di, ay * di, az * di, aw * di);
        u[(size_t)node * 16 + q] = r;
        if (us) {
            float4 r2 = make_float4(r.x * di, r.y * di, r.z * di, r.w * di);
            us[(size_t)node * 16 + q] = r2;
        }
    }
}

// ----------------------------- attn + fusion tail --------------------------
// mean_fused == h (branch coeffs sum to [3,0,0]); attn_fused = ca*h+cb*u1+cc*u2

__global__ __launch_bounds__(256) void attnfuse_k(const float4* __restrict__ h,
                                                  const float4* __restrict__ u1,
                                                  const float4* __restrict__ u2,
                                                  const float4* __restrict__ res,
                                                  const float* __restrict__ Wattn,
                                                  const float* __restrict__ battn,
                                                  const float* __restrict__ Wf1,
                                                  const float* __restrict__ bf1,
                                                  const float* __restrict__ Wf2,
                                                  const float* __restrict__ bf2,
                                                  const float* __restrict__ W3,
                                                  const float* __restrict__ b3,
                                                  const float* __restrict__ W4,
                                                  const float* __restrict__ b4,
                                                  float2* __restrict__ out, int N) {
    int n = blockIdx.x * 256 + threadIdx.x;
    if (n >= N) return;
    const float4* H = h + (size_t)n * 16;
    const float4* A = u1 + (size_t)n * 16;
    const float4* Bv = u2 + (size_t)n * 16;
    const float4* R = res + (size_t)n * 16;
    const float4* Wa = (const float4*)Wattn;
    float4 Hr[16];
    float th = 0.f, ta = 0.f, tb = 0.f;
    #pragma unroll
    for (int j = 0; j < 16; j++) {
        float4 hv = H[j], av = A[j], bv = Bv[j], w = Wa[j];
        Hr[j] = hv;
        th += hv.x * w.x + hv.y * w.y + hv.z * w.z + hv.w * w.w;
        ta += av.x * w.x + av.y * w.y + av.z * w.z + av.w * w.w;
        tb += bv.x * w.x + bv.y * w.y + bv.z * w.z + bv.w * w.w;
    }
    float ba = battn[0];
    float s0 = 0.75f * th + 1.5f * ta + 0.75f * tb + ba;
    float s1 = 1.5f * th - 1.5f * tb + ba;
    float s2 = 0.75f * th - 1.5f * ta + 0.75f * tb + ba;
    float m = fmaxf(s0, fmaxf(s1, s2));
    float e0 = expf(s0 - m), e1 = expf(s1 - m), e2 = expf(s2 - m);
    float inv = 1.f / (e0 + e1 + e2);
    float w0 = e0 * inv, w1 = e1 * inv, w2 = e2 * inv;
    float ca = 0.75f * w0 + 1.5f * w1 + 0.75f * w2;
    float cb = 1.5f * (w0 - w2);
    float cc = 0.75f * w0 - 1.5f * w1 + 0.75f * w2;
    // t = relu([af | h] @ Wf1 + bf1), af computed on the fly
    const float4* Wf14 = (const float4*)Wf1;
    const float4* Bf1 = (const float4*)bf1;
    float4 t[16];
    #pragma unroll
    for (int j = 0; j < 16; j++) t[j] = Bf1[j];
    #pragma unroll 1
    for (int kc = 0; kc < 16; kc++) {
        float4 hv = Hr[kc], av = A[kc], bv = Bv[kc];
        float4 af;
        af.x = ca * hv.x + cb * av.x + cc * bv.x;
        af.y = ca * hv.y + cb * av.y + cc * bv.y;
        af.z = ca * hv.z + cb * av.z + cc * bv.z;
        af.w = ca * hv.w + cb * av.w + cc * bv.w;
        const float4* wa = Wf14 + kc * 64;
        const float4* wh = Wf14 + (16 + kc) * 64;
        #pragma unroll
        for (int j = 0; j < 16; j++) {
            fma4(t[j], af.x, wa[j]);
            fma4(t[j], af.y, wa[16 + j]);
            fma4(t[j], af.z, wa[32 + j]);
            fma4(t[j], af.w, wa[48 + j]);
            fma4(t[j], hv.x, wh[j]);
            fma4(t[j], hv.y, wh[16 + j]);
            fma4(t[j], hv.z, wh[32 + j]);
            fma4(t[j], hv.w, wh[48 + j]);
        }
    }
    const float4* Wf24 = (const float4*)Wf2;
    float fwacc = bf2[0];
    #pragma unroll
    for (int j = 0; j < 16; j++) {
        float4 v = t[j];
        v.x = fmaxf(v.x, 0.f); v.y = fmaxf(v.y, 0.f);
        v.z = fmaxf(v.z, 0.f); v.w = fmaxf(v.w, 0.f);
        float4 w = Wf24[j];
        fwacc += v.x * w.x + v.y * w.y + v.z * w.z + v.w * w.w;
    }
    float fw = 1.f / (1.f + expf(-fwacc));
    float c_af = 0.1f * fw, c_mf = 1.f - fw;
    // g = relu(fused @ W3 + b3), fused = c_af*af + c_mf*h + 0.8*res
    const float4* W34 = (const float4*)W3;
    const float4* B3 = (const float4*)b3;
    float4 g[16];
    #pragma unroll
    for (int j = 0; j < 16; j++) g[j] = B3[j];
    #pragma unroll 1
    for (int kc = 0; kc < 16; kc++) {
        float4 hv = Hr[kc], av = A[kc], bv = Bv[kc], rv = R[kc];
        float4 f;
        f.x = c_af * (ca * hv.x + cb * av.x + cc * bv.x) + c_mf * hv.x + 0.8f * rv.x;
        f.y = c_af * (ca * hv.y + cb * av.y + cc * bv.y) + c_mf * hv.y + 0.8f * rv.y;
        f.z = c_af * (ca * hv.z + cb * av.z + cc * bv.z) + c_mf * hv.z + 0.8f * rv.z;
        f.w = c_af * (ca * hv.w + cb * av.w + cc * bv.w) + c_mf * hv.w + 0.8f * rv.w;
        const float4* wrow = W34 + kc * 64;
        #pragma unroll
        for (int j = 0; j < 16; j++) {
            fma4(g[j], f.x, wrow[j]);
            fma4(g[j], f.y, wrow[16 + j]);
            fma4(g[j], f.z, wrow[32 + j]);
            fma4(g[j], f.w, wrow[48 + j]);
        }
    }
    const float2* W42 = (const float2*)W4;
    float l0 = b4[0], l1 = b4[1];
    #pragma unroll
    for (int j = 0; j < 16; j++) {
        float4 v = g[j];
        v.x = fmaxf(v.x, 0.f); v.y = fmaxf(v.y, 0.f);
        v.z = fmaxf(v.z, 0.f); v.w = fmaxf(v.w, 0.f);
        float2 wa = W42[j * 4 + 0], wb = W42[j * 4 + 1];
        float2 wc = W42[j * 4 + 2], wd = W42[j * 4 + 3];
        l0 += v.x * wa.x + v.y * wb.x + v.z * wc.x + v.w * wd.x;
        l1 += v.x * wa.y + v.y * wb.y + v.z * wc.y + v.w * wd.y;
    }
    out[n] = make_float2(l0, l1);
}

// ----------------------------- launch --------------------------------------

extern "C" void kernel_launch(void* const* d_in, const int* in_sizes, int n_in,
                              void* d_out, int out_size, void* d_ws, size_t ws_size,
                              hipStream_t stream) {
    const float* in_feat = (const float*)d_in[0];
    const int*   src     = (const int*)d_in[1];
    const int*   dst     = (const int*)d_in[2];
    const float* W1   = (const float*)d_in[3];
    const float* b1   = (const float*)d_in[4];
    const float* W2   = (const float*)d_in[5];
    const float* b2   = (const float*)d_in[6];
    const float* Wres = (const float*)d_in[7];
    const float* bres = (const float*)d_in[8];
    const float* Wattn = (const float*)d_in[9];
    const float* battn = (const float*)d_in[10];
    const float* Wf1  = (const float*)d_in[11];
    const float* bf1  = (const float*)d_in[12];
    const float* Wf2  = (const float*)d_in[13];
    const float* bf2  = (const float*)d_in[14];
    const float* W3   = (const float*)d_in[15];
    const float* b3   = (const float*)d_in[16];
    const float* W4   = (const float*)d_in[17];
    const float* b4   = (const float*)d_in[18];

    const int N = in_sizes[0] / 128;
    const int E = in_sizes[1];
    const int B = (N + BNODES - 1) >> BSHIFT;

    char* p = (char*)d_ws;
    auto take = [&](size_t bytes) -> char* {
        char* r = p;
        p += (bytes + 255) & ~(size_t)255;
        return r;
    };
    int*   bucketCount  = (int*)take((size_t)(B + 1) * 4);
    int*   bucketPtr    = (int*)take((size_t)(B + 1) * 4);
    int*   bucketCursor = (int*)take((size_t)(B + 1) * 4);
    int*   rowPtr       = (int*)take((size_t)(N + 1) * 4);
    float* dinv         = (float*)take((size_t)N * 4);
    int*   srcSorted    = (int*)take((size_t)E * 4);
    float* h1  = (float*)take((size_t)N * 256);
    float* h   = (float*)take((size_t)N * 256);
    float* hs  = (float*)take((size_t)N * 256);
    float* u1s = (float*)take((size_t)N * 256);
    float* res = (float*)take((size_t)N * 256);
    float* u1  = (float*)take((size_t)N * 256);
    int*   ebuf = (int*)h1;   // dead before dense1 writes h1 (stream-ordered)
    float* u2  = h1;          // h1 dead after dense2res reads it

    int eb = (E + CHUNK - 1) / CHUNK;
    int nb = (N + 255) / 256;
    int sb = ((N * 64) + 255) / 256;

    hipMemsetAsync(bucketCount, 0, (size_t)B * 4, stream);
    bucket_count_k<<<eb, 256, 0, stream>>>(dst, bucketCount, E, B);
    bucket_scan_k<<<1, 64, 0, stream>>>(bucketCount, bucketPtr, bucketCursor,
                                        rowPtr, B, N, E);
    bucket_scatter_k<<<eb, 256, 0, stream>>>(src, dst, bucketCursor, ebuf, E, B);
    csr_build_k<<<B, 256, 0, stream>>>(ebuf, bucketPtr, rowPtr, dinv, srcSorted, N);

    dense1_k<<<nb, 256, 0, stream>>>(in_feat, W1, b1, h1, N);
    dense2res_k<<<nb, 256, 0, stream>>>(h1, W2, b2, Wres, bres, dinv, h, hs, res, N);

    spmm_k<<<sb, 256, 0, stream>>>((const float4*)hs, srcSorted, rowPtr, dinv,
                                   (float4*)u1, (float4*)u1s, N);
    spmm_k<<<sb, 256, 0, stream>>>((const float4*)u1s, srcSorted, rowPtr, dinv,
                                   (float4*)u2, nullptr, N);

    attnfuse_k<<<nb, 256, 0, stream>>>((const float4*)h, (const float4*)u1,
                                       (const float4*)u2, (const float4*)res,
                                       Wattn, battn, Wf1, bf1, Wf2, bf2,
                                       W3, b3, W4, b4, (float2*)d_out, N);
}